// Round 2
// baseline (1446.987 us; speedup 1.0000x reference)
//
#include <hip/hip_runtime.h>
#include <hip/hip_bf16.h>
#include <stdint.h>

// BinaryLinearLayer: out = sign(x) @ sign(w), x:[N,4096] f32, w:[4096,4096] f32.
// Exact integer path: pack sign bits (bit=1 iff v<0), dot = K - 2*popc(a^b).

#define DIN   4096
#define DOUT  4096
#define KW    (DIN / 32)   // 128 k-words
#define BM    128
#define BN    128
#define BKW   32           // k-words per LDS tile (1024 k-bits)
#define PAD   4            // keeps 16B alignment of row starts, breaks pow2 stride

// ---- pack x: one wave per row-chunk, ballot builds 64 k-bits at a time ----
__global__ __launch_bounds__(256) void pack_x_kernel(const float* __restrict__ x,
                                                     uint32_t* __restrict__ xp) {
    const int wave = threadIdx.x >> 6;   // 0..3
    const int lane = threadIdx.x & 63;
    const int n = blockIdx.x * 4 + wave;
    const float* row = x + (size_t)n * DIN;
    unsigned long long* dst = (unsigned long long*)xp + (size_t)n * (KW / 2);
    #pragma unroll 4
    for (int c = 0; c < DIN / 64; c++) {
        float v = row[c * 64 + lane];
        unsigned long long m = __ballot(v < 0.0f);   // bit i = lane i = k offset i
        if (lane == 0) dst[c] = m;
    }
}

// ---- pack w: wp layout [kc][out] (kc-major) so GEMM B-tile loads coalesce ----
__global__ __launch_bounds__(256) void pack_w_kernel(const float* __restrict__ w,
                                                     uint32_t* __restrict__ wp) {
    const int out = blockIdx.x * 256 + threadIdx.x;
    const int kc  = blockIdx.y;                      // 0..KW-1
    const float* base = w + (size_t)(kc * 32) * DOUT + out;
    uint32_t word = 0;
    #pragma unroll
    for (int j = 0; j < 32; j++) {
        word |= (base[(size_t)j * DOUT] < 0.0f ? 1u : 0u) << j;
    }
    wp[(size_t)kc * DOUT + out] = word;
}

// ---- bit-GEMM: C[n][o] = DIN - 2 * sum_kc popc(xp[n][kc] ^ wp[kc][o]) ----
// Thread tile: rows {ty*4..+3, 64+ty*4..+3} x cols {tx*4..+3, 64+tx*4..+3}
// so every LDS fragment read is a contiguous, 16B-aligned ds_read_b128.
__global__ __launch_bounds__(256, 4) void bgemm_kernel(const uint32_t* __restrict__ xp,
                                                       const uint32_t* __restrict__ wp,
                                                       float* __restrict__ out) {
    __shared__ uint32_t xs[BKW][BM + PAD];   // [kword][row], stride 132 words
    __shared__ uint32_t ws[BKW][BN + PAD];   // [kword][col]

    const int t  = threadIdx.x;
    const int bm = blockIdx.y * BM;
    const int bn = blockIdx.x * BN;
    const int tx = t & 15;
    const int ty = t >> 4;
    const int r0 = ty * 4;            // rows r0..r0+3 and r0+64..r0+67
    const int c0 = tx * 4;            // cols c0..c0+3 and c0+64..c0+67

    const uint4* xp4 = (const uint4*)xp;   // [row][KW/4]
    const uint4* wp4 = (const uint4*)wp;   // [kc][DOUT/4]

    int acc[8][8];
    #pragma unroll
    for (int i = 0; i < 8; i++)
        #pragma unroll
        for (int j = 0; j < 8; j++) acc[i][j] = 0;

    for (int kw0 = 0; kw0 < KW; kw0 += BKW) {
        // A-tile: 128 rows x 32 words -> transposed [kword][row].
        // Each thread: 4 coalesced uint4 loads, 16 scalar LDS writes.
        #pragma unroll
        for (int it = 0; it < 4; it++) {
            int idx = t + it * 256;           // 0..1023
            int q   = idx & 7;                // kword-quad within row
            int r   = idx >> 3;               // 0..127
            uint4 v = xp4[(bm + r) * (KW / 4) + (kw0 >> 2) + q];
            xs[q * 4 + 0][r] = v.x;
            xs[q * 4 + 1][r] = v.y;
            xs[q * 4 + 2][r] = v.z;
            xs[q * 4 + 3][r] = v.w;
        }
        // B-tile: 32 kwords x 128 cols, natural layout, uint4 in/out.
        #pragma unroll
        for (int it = 0; it < 4; it++) {
            int idx = t + it * 256;           // 0..1023
            int cq  = idx & 31;               // col-quad
            int kc  = idx >> 5;               // 0..31
            uint4 v = wp4[(kw0 + kc) * (DOUT / 4) + (bn >> 2) + cq];
            *(uint4*)&ws[kc][cq * 4] = v;
        }
        __syncthreads();

        for (int kc = 0; kc < BKW; kc++) {
            uint32_t a[8], b[8];
            *(uint4*)&a[0] = *(const uint4*)&xs[kc][r0];        // broadcast
            *(uint4*)&a[4] = *(const uint4*)&xs[kc][r0 + 64];
            *(uint4*)&b[0] = *(const uint4*)&ws[kc][c0];        // 2-way, free
            *(uint4*)&b[4] = *(const uint4*)&ws[kc][c0 + 64];
            #pragma unroll
            for (int i = 0; i < 8; i++)
                #pragma unroll
                for (int j = 0; j < 8; j++)
                    acc[i][j] += __popc(a[i] ^ b[j]);
        }
        __syncthreads();
    }

    // epilogue: C = K - 2*popc_sum, float4 stores (lanes tx contiguous)
    #pragma unroll
    for (int i = 0; i < 8; i++) {
        int row = bm + (i < 4 ? r0 + i : 64 + r0 + (i - 4));
        float* o = out + (size_t)row * DOUT + bn;
        float4 v0 = make_float4((float)(DIN - 2 * acc[i][0]), (float)(DIN - 2 * acc[i][1]),
                                (float)(DIN - 2 * acc[i][2]), (float)(DIN - 2 * acc[i][3]));
        float4 v1 = make_float4((float)(DIN - 2 * acc[i][4]), (float)(DIN - 2 * acc[i][5]),
                                (float)(DIN - 2 * acc[i][6]), (float)(DIN - 2 * acc[i][7]));
        *(float4*)(o + c0)      = v0;
        *(float4*)(o + 64 + c0) = v1;
    }
}

extern "C" void kernel_launch(void* const* d_in, const int* in_sizes, int n_in,
                              void* d_out, int out_size, void* d_ws, size_t ws_size,
                              hipStream_t stream) {
    const float* x = (const float*)d_in[0];
    const float* w = (const float*)d_in[1];
    float* out = (float*)d_out;
    const int N = in_sizes[0] / DIN;       // 8192

    uint32_t* xp = (uint32_t*)d_ws;                                  // N*128 words = 4 MB
    uint32_t* wp = (uint32_t*)((char*)d_ws + (size_t)N * KW * 4);    // 128*4096 words = 2 MB

    pack_x_kernel<<<N / 4, 256, 0, stream>>>(x, xp);
    pack_w_kernel<<<dim3(DOUT / 256, KW), 256, 0, stream>>>(w, wp);
    bgemm_kernel<<<dim3(DOUT / BN, N / BM), 256, 0, stream>>>(xp, wp, out);
}

// Round 3
// 521.147 us; speedup vs baseline: 2.7765x; 2.7765x over previous
//
#include <hip/hip_runtime.h>
#include <hip/hip_bf16.h>
#include <stdint.h>

// BinaryLinearLayer: out = sign(x) @ sign(w), x:[N,4096] f32, w:[4096,4096] f32.
// Exact integer path: pack sign bits (bit=1 iff v<0), dot = K - 2*popc(a^b).

#define DIN   4096
#define DOUT  4096
#define KW    (DIN / 32)   // 128 k-words
#define BM    128
#define BN    128
#define BKW   32           // k-words per LDS tile (1024 k-bits)
#define PAD   4            // keeps 16B alignment of row starts, breaks pow2 stride

// ---- pack x: one wave per row-chunk, ballot builds 64 k-bits at a time ----
__global__ __launch_bounds__(256) void pack_x_kernel(const float* __restrict__ x,
                                                     uint32_t* __restrict__ xp) {
    const int wave = threadIdx.x >> 6;   // 0..3
    const int lane = threadIdx.x & 63;
    const int n = blockIdx.x * 4 + wave;
    const float* row = x + (size_t)n * DIN;
    unsigned long long* dst = (unsigned long long*)xp + (size_t)n * (KW / 2);
    #pragma unroll 4
    for (int c = 0; c < DIN / 64; c++) {
        float v = row[c * 64 + lane];
        unsigned long long m = __ballot(v < 0.0f);   // bit i = lane i = k offset i
        if (lane == 0) dst[c] = m;
    }
}

// ---- pack w: wp layout [kc][out] (kc-major) so GEMM B-tile loads coalesce ----
__global__ __launch_bounds__(256) void pack_w_kernel(const float* __restrict__ w,
                                                     uint32_t* __restrict__ wp) {
    const int out = blockIdx.x * 256 + threadIdx.x;
    const int kc  = blockIdx.y;                      // 0..KW-1
    const float* base = w + (size_t)(kc * 32) * DOUT + out;
    uint32_t word = 0;
    #pragma unroll
    for (int j = 0; j < 32; j++) {
        word |= (base[(size_t)j * DOUT] < 0.0f ? 1u : 0u) << j;
    }
    wp[(size_t)kc * DOUT + out] = word;
}

// ---- bit-GEMM: C[n][o] = DIN - 2 * sum_kc popc(xp[n][kc] ^ wp[kc][o]) ----
// Thread tile: rows {ty*4..+3, 64+ty*4..+3} x cols {tx*4..+3, 64+tx*4..+3}
// so every LDS fragment read is a contiguous, 16B-aligned ds_read_b128.
// launch_bounds(256,3): budget ~168 VGPR — need ~130 (64 acc + 16 frag +
// staging); (256,4)'s 128-cap forced a catastrophic acc spill (round 2).
__global__ __launch_bounds__(256, 3) void bgemm_kernel(const uint32_t* __restrict__ xp,
                                                       const uint32_t* __restrict__ wp,
                                                       float* __restrict__ out) {
    __shared__ uint32_t xs[BKW][BM + PAD];   // [kword][row], stride 132 words
    __shared__ uint32_t ws[BKW][BN + PAD];   // [kword][col]

    const int t  = threadIdx.x;
    const int bm = blockIdx.y * BM;
    const int bn = blockIdx.x * BN;
    const int tx = t & 15;
    const int ty = t >> 4;
    const int r0 = ty * 4;            // rows r0..r0+3 and r0+64..r0+67
    const int c0 = tx * 4;            // cols c0..c0+3 and c0+64..c0+67

    const uint4* xp4 = (const uint4*)xp;   // [row][KW/4]
    const uint4* wp4 = (const uint4*)wp;   // [kc][DOUT/4]

    int acc[8][8];
    #pragma unroll
    for (int i = 0; i < 8; i++)
        #pragma unroll
        for (int j = 0; j < 8; j++) acc[i][j] = 0;

    for (int kw0 = 0; kw0 < KW; kw0 += BKW) {
        // A-tile: 128 rows x 32 words -> transposed [kword][row].
        #pragma unroll
        for (int it = 0; it < 4; it++) {
            int idx = t + it * 256;           // 0..1023
            int q   = idx & 7;                // kword-quad within row
            int r   = idx >> 3;               // 0..127
            uint4 v = xp4[(bm + r) * (KW / 4) + (kw0 >> 2) + q];
            xs[q * 4 + 0][r] = v.x;
            xs[q * 4 + 1][r] = v.y;
            xs[q * 4 + 2][r] = v.z;
            xs[q * 4 + 3][r] = v.w;
        }
        // B-tile: 32 kwords x 128 cols, natural layout, uint4 in/out.
        #pragma unroll
        for (int it = 0; it < 4; it++) {
            int idx = t + it * 256;           // 0..1023
            int cq  = idx & 31;               // col-quad
            int kc  = idx >> 5;               // 0..31
            uint4 v = wp4[(kw0 + kc) * (DOUT / 4) + (bn >> 2) + cq];
            *(uint4*)&ws[kc][cq * 4] = v;
        }
        __syncthreads();

        // unroll 2: enough ILP to pipeline, small enough to avoid spill
        #pragma unroll 2
        for (int kc = 0; kc < BKW; kc++) {
            uint32_t a[8], b[8];
            *(uint4*)&a[0] = *(const uint4*)&xs[kc][r0];        // broadcast
            *(uint4*)&a[4] = *(const uint4*)&xs[kc][r0 + 64];
            *(uint4*)&b[0] = *(const uint4*)&ws[kc][c0];        // 2-way, free
            *(uint4*)&b[4] = *(const uint4*)&ws[kc][c0 + 64];
            #pragma unroll
            for (int i = 0; i < 8; i++)
                #pragma unroll
                for (int j = 0; j < 8; j++)
                    acc[i][j] += __popc(a[i] ^ b[j]);
        }
        __syncthreads();
    }

    // epilogue: C = K - 2*popc_sum, float4 stores (lanes tx contiguous)
    #pragma unroll
    for (int i = 0; i < 8; i++) {
        int row = bm + (i < 4 ? r0 + i : 64 + r0 + (i - 4));
        float* o = out + (size_t)row * DOUT + bn;
        float4 v0 = make_float4((float)(DIN - 2 * acc[i][0]), (float)(DIN - 2 * acc[i][1]),
                                (float)(DIN - 2 * acc[i][2]), (float)(DIN - 2 * acc[i][3]));
        float4 v1 = make_float4((float)(DIN - 2 * acc[i][4]), (float)(DIN - 2 * acc[i][5]),
                                (float)(DIN - 2 * acc[i][6]), (float)(DIN - 2 * acc[i][7]));
        *(float4*)(o + c0)      = v0;
        *(float4*)(o + 64 + c0) = v1;
    }
}

extern "C" void kernel_launch(void* const* d_in, const int* in_sizes, int n_in,
                              void* d_out, int out_size, void* d_ws, size_t ws_size,
                              hipStream_t stream) {
    const float* x = (const float*)d_in[0];
    const float* w = (const float*)d_in[1];
    float* out = (float*)d_out;
    const int N = in_sizes[0] / DIN;       // 8192

    uint32_t* xp = (uint32_t*)d_ws;                                  // N*128 words = 4 MB
    uint32_t* wp = (uint32_t*)((char*)d_ws + (size_t)N * KW * 4);    // 128*4096 words = 2 MB

    pack_x_kernel<<<N / 4, 256, 0, stream>>>(x, xp);
    pack_w_kernel<<<dim3(DOUT / 256, KW), 256, 0, stream>>>(w, wp);
    bgemm_kernel<<<dim3(DOUT / BN, N / BM), 256, 0, stream>>>(xp, wp, out);
}

// Round 4
// 408.603 us; speedup vs baseline: 3.5413x; 1.2754x over previous
//
#include <hip/hip_runtime.h>
#include <stdint.h>

// BinaryLinearLayer: out = sign(x) @ sign(w), x:[8192,4096] f32, w:[4096,4096] f32.
// Exact path via i8 MFMA: sign -> +/-1 int8, v_mfma_i32_16x16x64_i8, i32 acc
// (K-sums <= 4096, exact). Popcount path was at its roofline (v_bcnt not
// full-rate: 287us @ 86% VALUBusy = ~9cyc/MAC); i8 MFMA floor is 70us.

#define DIN  4096
#define DOUT 4096
#define BM   128
#define BN   128
#define BK   64     // i8 k-elems per LDS tile = one 16x16x64 MFMA k-step

typedef __attribute__((ext_vector_type(4))) int v4i;
typedef unsigned int u32;

__device__ __forceinline__ void cp16(void* lds, const void* g) {
    __builtin_amdgcn_global_load_lds((const __attribute__((address_space(1))) u32*)g,
                                     (__attribute__((address_space(3))) u32*)lds,
                                     16, 0, 0);
}

// ---- x [N,DIN] f32 -> xb [N,DIN] i8 (+1/-1), fully coalesced ----
__global__ __launch_bounds__(256) void pack_x_i8(const float* __restrict__ x,
                                                 signed char* __restrict__ xb) {
    size_t i = (size_t)blockIdx.x * 256 + threadIdx.x;
    float4 v = ((const float4*)x)[i];
    char4 s;
    s.x = v.x >= 0.f ? 1 : -1;
    s.y = v.y >= 0.f ? 1 : -1;
    s.z = v.z >= 0.f ? 1 : -1;
    s.w = v.w >= 0.f ? 1 : -1;
    ((char4*)xb)[i] = s;
}

// ---- w [DIN,DOUT] f32 -> wbT [DOUT,DIN] i8: wbT[n][k] = sign(w[k][n]) ----
// 64x64 tile transpose through LDS; coalesced read (along n) and write (along k).
__global__ __launch_bounds__(256) void pack_wT_i8(const float* __restrict__ w,
                                                  signed char* __restrict__ wbT) {
    __shared__ signed char tile[64][80];   // stride 80: 16B-aligned rows, breaks pow2
    const int k0 = blockIdx.y * 64, n0 = blockIdx.x * 64;
    const int t = threadIdx.x;
    const int j  = t & 63;    // n offset
    const int i0 = t >> 6;    // 0..3
    #pragma unroll
    for (int s = 0; s < 16; s++) {
        int i = i0 + s * 4;   // k offset
        float v = w[(size_t)(k0 + i) * DOUT + n0 + j];
        tile[j][i] = v >= 0.f ? 1 : -1;
    }
    __syncthreads();
    const int n  = t >> 2;          // 0..63
    const int kk = (t & 3) * 16;    // byte offset within row
    v4i val = *(const v4i*)&tile[n][kk];                       // 80n+16q: 16B aligned
    *(v4i*)&wbT[(size_t)(n0 + n) * DIN + k0 + kk] = val;
}

// ---- i8 MFMA GEMM, m97-clone geometry ----
// 256 thr = 4 waves (2x2 wave grid, 64x64/wave = 4x4 MFMA 16x16 tiles).
// LDS tiles: As[128 rows][64B], Bs[128 n][64B] (B pre-transposed in wbT).
// Staging: 2x global_load_lds_dwordx4 per thread per operand (wave-uniform
// base + lane*16 == row-major [row][64B] exactly).
// Fragments: A[m=lane&15][k=quad*16+j] = 16B @ m*64+quad*16 (verified-geometry
// analog of bf16 16x16x32); C/D col=lane&15,row=quad*4+reg (HW-verified,
// dtype-independent).
__global__ __launch_bounds__(256) void bgemm_i8(const signed char* __restrict__ xb,
                                                const signed char* __restrict__ wbT,
                                                float* __restrict__ out) {
    __shared__ signed char As[BM * BK];   // 8 KB
    __shared__ signed char Bs[BN * BK];   // 8 KB

    const int t = threadIdx.x;
    const int w = t >> 6, l = t & 63;
    const int bm = blockIdx.y * BM, bn = blockIdx.x * BN;
    const int wm = (w & 1) * 64, wn = (w >> 1) * 64;
    const int m = l & 15, quad = l >> 4;

    const signed char* gA = xb  + (size_t)(bm + w * 16 + (l >> 2)) * DIN + (l & 3) * 16;
    const signed char* gB = wbT + (size_t)(bn + w * 16 + (l >> 2)) * DIN + (l & 3) * 16;
    signed char* lA = As + w * 1024 + l * 16;
    signed char* lB = Bs + w * 1024 + l * 16;

    v4i acc[4][4];
    #pragma unroll
    for (int i = 0; i < 4; i++)
        #pragma unroll
        for (int j = 0; j < 4; j++) {
            v4i z = {0, 0, 0, 0};
            acc[i][j] = z;
        }

    for (int k0 = 0; k0 < DIN; k0 += BK) {
        cp16(lA,        gA + k0);                          // rows  0..63 of A-tile
        cp16(lA + 4096, gA + (size_t)64 * DIN + k0);       // rows 64..127
        cp16(lB,        gB + k0);
        cp16(lB + 4096, gB + (size_t)64 * DIN + k0);
        __syncthreads();

        v4i a[4], b[4];
        #pragma unroll
        for (int i = 0; i < 4; i++)
            a[i] = *(const v4i*)&As[(wm + i * 16 + m) * 64 + quad * 16];
        #pragma unroll
        for (int j = 0; j < 4; j++)
            b[j] = *(const v4i*)&Bs[(wn + j * 16 + m) * 64 + quad * 16];
        #pragma unroll
        for (int i = 0; i < 4; i++)
            #pragma unroll
            for (int j = 0; j < 4; j++)
                acc[i][j] = __builtin_amdgcn_mfma_i32_16x16x64_i8(a[i], b[j], acc[i][j], 0, 0, 0);
        __syncthreads();
    }

    // epilogue: C/D col=lane&15, row=quad*4+reg (verified dtype-independent)
    #pragma unroll
    for (int i = 0; i < 4; i++) {
        int row0 = bm + wm + i * 16 + quad * 4;
        #pragma unroll
        for (int j = 0; j < 4; j++) {
            int col = bn + wn + j * 16 + m;
            #pragma unroll
            for (int r = 0; r < 4; r++)
                out[(size_t)(row0 + r) * DOUT + col] = (float)acc[i][j][r];
        }
    }
}

extern "C" void kernel_launch(void* const* d_in, const int* in_sizes, int n_in,
                              void* d_out, int out_size, void* d_ws, size_t ws_size,
                              hipStream_t stream) {
    const float* x = (const float*)d_in[0];
    const float* w = (const float*)d_in[1];
    float* out = (float*)d_out;
    const int N = in_sizes[0] / DIN;                       // 8192

    signed char* xb  = (signed char*)d_ws;                 // 32 MB
    signed char* wbT = (signed char*)d_ws + (size_t)N * DIN;  // 16 MB

    pack_x_i8<<<(N * DIN) / 1024, 256, 0, stream>>>(x, xb);
    pack_wT_i8<<<dim3(DOUT / 64, DIN / 64), 256, 0, stream>>>(w, wbT);
    bgemm_i8<<<dim3(DOUT / BN, N / BM), 256, 0, stream>>>(xb, wbT, out);
}